// Round 7
// baseline (110.118 us; speedup 1.0000x reference)
//
#include <hip/hip_runtime.h>

// Viterbi trellis quantizer: S=1024 states, K=2 (4 preds), CHUNK=4,
// T=64 steps/chain, B=4096 chains (16x16 blocks of a 1024^2 array).
//
// Structure (R7): 2 waves per chain (128-thread block), thread owns groups
// q0=2tid, q1=2tid+1. Grouped-max M in ping-pong LDS buffers, 1 barrier/step.
// R6 showed 4 waves/chain serializes LDS and VALU phases (VALUBusy 65%);
// R5 showed 2 waves/chain reaches 96% busy but suffered ~2x inst bloat at
// VGPR_Count=32 (AGPR shuttling). Fix here: live set ~55 regs (codebook
// packed v2f over the q-pair = 40 regs) + amdgpu_waves_per_eu(8) pins the
// allocator at the 64-reg tier it needs; packed fp32 (v_pk_fma/add) halves
// the arithmetic op count; unroll-2 folds ping-pong offsets into LDS
// immediates (zero per-step address VALU).
//
// beta-form: M_t[q] = max_j ( M_{t-1}[(q>>2)+64j] + cb[q+256j]·x_t + h ),
// h = -||cb||^2/2. J[t][q] = argmax_j (2 bits; 2 steps x 2 groups per byte).
// Traceback: s_t = p + 256*J[t][p], p = s_{t+1}>>2.

typedef float v2f __attribute__((ext_vector_type(2)));

#define COLS      1024
#define T_STEPS   64
#define REC_SIZE  (1024 * 1024)

__global__ __launch_bounds__(128)
__attribute__((amdgpu_waves_per_eu(8)))
void viterbi_q(
    const float* __restrict__ arr,
    const float* __restrict__ cbook,
    float* __restrict__ out)
{
    const int tid   = threadIdx.x;   // owns state-groups 2tid, 2tid+1
    const int wid   = tid >> 6;
    const int lane  = tid & 63;
    const int chain = blockIdx.x;    // 0..4095
    const int rb    = chain >> 6;    // block-row
    const int cbc   = chain & 63;    // block-col

    __shared__ __align__(16) float tile[256];    // x chunks
    __shared__ __align__(16) float Mb[2][256];   // ping-pong grouped-max M
    __shared__ unsigned char J[32 * 128];        // backpointers, 2 steps/byte
    __shared__ int   st_lds[64];                 // traced-back states
    __shared__ float redv[2];
    __shared__ int   reds[2];

    // ---- stage the 16x16 tile ----
    if (tid < 64) {
        const int r  = tid >> 2;
        const int c4 = (tid & 3) << 2;
        *(float4*)&tile[tid << 2] =
            *(const float4*)(arr + (rb * 16 + r) * COLS + cbc * 16 + c4);
    }
    // M(-1) = 0: iteration t=0 then yields beta0 = cb·x0 + h exactly.
    *(float2*)&Mb[0][tid << 1] = make_float2(0.f, 0.f);

    // ---- codebook rows for q0,q1 packed as v2f per j: s = 2tid + c + 256j ----
    v2f ax[4], ay[4], az[4], aw[4], hh[4];
    #pragma unroll
    for (int j = 0; j < 4; ++j) {
        float4 r0 = *(const float4*)(cbook + (2 * tid     + 256 * j) * 4);
        float4 r1 = *(const float4*)(cbook + (2 * tid + 1 + 256 * j) * 4);
        ax[j] = (v2f){r0.x, r1.x};  ay[j] = (v2f){r0.y, r1.y};
        az[j] = (v2f){r0.z, r1.z};  aw[j] = (v2f){r0.w, r1.w};
        hh[j] = (v2f){ -0.5f * (r0.x*r0.x + r0.y*r0.y + r0.z*r0.z + r0.w*r0.w),
                       -0.5f * (r1.x*r1.x + r1.y*r1.y + r1.z*r1.z + r1.w*r1.w) };
    }
    __syncthreads();

    const int pg = tid >> 1;   // predecessor base group (shared by q0,q1)
    unsigned nib = 0;

    auto step = [&](int t, const float* __restrict__ Mr, float* __restrict__ Mw) {
        const float4 xt = *(const float4*)&tile[t << 2];   // uniform broadcast
        const float m0 = Mr[pg], m1 = Mr[pg + 64],
                    m2 = Mr[pg + 128], m3 = Mr[pg + 192];
        const v2f xx = (v2f){xt.x, xt.x}, yy = (v2f){xt.y, xt.y},
                  zz = (v2f){xt.z, xt.z}, ww = (v2f){xt.w, xt.w};
        v2f cand[4];
        const float mj[4] = {m0, m1, m2, m3};
        #pragma unroll
        for (int j = 0; j < 4; ++j) {
            v2f acc = __builtin_elementwise_fma(ax[j], xx, hh[j]);
            acc = __builtin_elementwise_fma(ay[j], yy, acc);
            acc = __builtin_elementwise_fma(az[j], zz, acc);
            acc = __builtin_elementwise_fma(aw[j], ww, acc);
            cand[j] = acc + (v2f){mj[j], mj[j]};
        }
        // first-max index per group (== reference first-min over alpha)
        const float v0 = fmaxf(fmaxf(cand[0].x, cand[1].x),
                               fmaxf(cand[2].x, cand[3].x));
        const int   j0 = (cand[0].x == v0) ? 0 : (cand[1].x == v0) ? 1
                       : (cand[2].x == v0) ? 2 : 3;
        const float v1 = fmaxf(fmaxf(cand[0].y, cand[1].y),
                               fmaxf(cand[2].y, cand[3].y));
        const int   j1 = (cand[0].y == v1) ? 0 : (cand[1].y == v1) ? 1
                       : (cand[2].y == v1) ? 2 : 3;
        *(float2*)&Mw[tid << 1] = make_float2(v0, v1);
        const unsigned nb = (unsigned)j0 | ((unsigned)j1 << 2);
        if (t & 1) J[(t >> 1) * 128 + tid] = (unsigned char)(nib | (nb << 4));
        else       nib = nb;
        __syncthreads();
    };

    // ---- forward recursion t = 0..62 (unroll 2: ping-pong phases fold) ----
    #pragma unroll 1
    for (int tt = 0; tt < 31; ++tt) {
        step(2 * tt,     Mb[0], Mb[1]);
        step(2 * tt + 1, Mb[1], Mb[0]);
    }
    step(62, Mb[0], Mb[1]);
    J[31 * 128 + tid] = (unsigned char)nib;   // t=62 nibble (low 4 bits)

    // ---- final step t = 63: full argmax over beta_63[0..1023] ----
    {
        const float* __restrict__ Mr = Mb[1];
        const float4 xt = *(const float4*)&tile[63 << 2];
        const float m0 = Mr[pg], m1 = Mr[pg + 64],
                    m2 = Mr[pg + 128], m3 = Mr[pg + 192];
        const v2f xx = (v2f){xt.x, xt.x}, yy = (v2f){xt.y, xt.y},
                  zz = (v2f){xt.z, xt.z}, ww = (v2f){xt.w, xt.w};
        const float mj[4] = {m0, m1, m2, m3};
        float bv = -3.4e38f;
        int   bs = 0;
        #pragma unroll
        for (int j = 0; j < 4; ++j) {     // s = 2tid + c + 256j: asc (j,c)
            v2f acc = __builtin_elementwise_fma(ax[j], xx, hh[j]);
            acc = __builtin_elementwise_fma(ay[j], yy, acc);
            acc = __builtin_elementwise_fma(az[j], zz, acc);
            acc = __builtin_elementwise_fma(aw[j], ww, acc);
            const float c0 = acc.x + mj[j], c1 = acc.y + mj[j];
            if (c0 > bv) { bv = c0; bs = 2 * tid     + (j << 8); }
            if (c1 > bv) { bv = c1; bs = 2 * tid + 1 + (j << 8); }
        }
        // lexicographic (value desc, state asc) butterfly within the wave
        #pragma unroll
        for (int off = 32; off > 0; off >>= 1) {
            const float ov = __shfl_xor(bv, off, 64);
            const int   os = __shfl_xor(bs, off, 64);
            if (ov > bv || (ov == bv && os < bs)) { bv = ov; bs = os; }
        }
        if (lane == 0) { redv[wid] = bv; reds[wid] = bs; }
    }
    __syncthreads();   // covers redv/reds and the J tail write

    // ---- traceback (serial, thread 0) ----
    if (tid == 0) {
        float bv = redv[0]; int bs = reds[0];
        if (redv[1] > bv || (redv[1] == bv && reds[1] < bs)) {
            bv = redv[1]; bs = reds[1];
        }
        int s = bs;
        st_lds[T_STEPS - 1] = s;
        for (int i = T_STEPS - 2; i >= 0; --i) {
            const int p = s >> 2;
            const unsigned byte = J[(i >> 1) * 128 + (p >> 1)];
            const int j = (byte >> (((i & 1) << 2) + ((p & 1) << 1))) & 3;
            s = p + (j << 8);
            st_lds[i] = s;
        }
    }
    __syncthreads();

    // ---- outputs ----
    if (tid < 64) {
        // rec: step t covers elements 4t..4t+3 -> row t>>2, cols 4*(t&3)..+3
        const int st = st_lds[tid];
        const float4 v = *(const float4*)(cbook + st * 4);
        const int r  = tid >> 2;
        const int c4 = (tid & 3) << 2;
        *(float4*)(out + (rb * 16 + r) * COLS + cbc * 16 + c4) = v;
    } else {
        // states flat: REC_SIZE + chain*64 + t (stored as float values)
        const int t = tid - 64;
        out[REC_SIZE + chain * 64 + t] = (float)st_lds[t];
    }
}

extern "C" void kernel_launch(void* const* d_in, const int* in_sizes, int n_in,
                              void* d_out, int out_size, void* d_ws, size_t ws_size,
                              hipStream_t stream)
{
    const float* arr   = (const float*)d_in[0];
    const float* cbook = (const float*)d_in[1];
    float* out = (float*)d_out;
    // one chain per 128-thread block (2 waves/chain), 4096 blocks
    viterbi_q<<<dim3(4096), dim3(128), 0, stream>>>(arr, cbook, out);
}